// Round 6
// baseline (514.883 us; speedup 1.0000x reference)
//
#include <hip/hip_runtime.h>
#include <hip/hip_bf16.h>

#define D 128

typedef __bf16 bf16x8 __attribute__((ext_vector_type(8)));
typedef __bf16 bf16x4 __attribute__((ext_vector_type(4)));
typedef __bf16 bf16x2 __attribute__((ext_vector_type(2)));
typedef float  f32x4  __attribute__((ext_vector_type(4)));
typedef float  f32x2  __attribute__((ext_vector_type(2)));

// ---------------------------------------------------------------------------
// Dtype probe: 1 = bf16-packed, 0 = fp32 (kept; R3-R5 evidence says bf16).
// ---------------------------------------------------------------------------
__global__ void detect_kernel(const unsigned int* __restrict__ w, int* flag)
{
    __shared__ int cnt[256];
    int c = 0;
#pragma unroll
    for (int i = 0; i < 4; ++i) {
        unsigned int v = w[threadIdx.x * 4 + i];
        unsigned int e = (v >> 7) & 0xFF;
        if (e >= 90 && e <= 134) ++c;
    }
    cnt[threadIdx.x] = c;
    __syncthreads();
    for (int s = 128; s > 0; s >>= 1) {
        if (threadIdx.x < s) cnt[threadIdx.x] += cnt[threadIdx.x + s];
        __syncthreads();
    }
    if (threadIdx.x == 0) flag[0] = (cnt[0] > 614) ? 1 : 0;
}

template <int ISBF>
__device__ __forceinline__ bf16x8 ld8(const void* p, size_t elem)
{
    if (ISBF) return *(const bf16x8*)((const __bf16*)p + elem);
    const f32x4* f = (const f32x4*)((const float*)p + elem);
    f32x4 lo = f[0], hi = f[1];
    bf16x8 r;
    r[0] = (__bf16)lo[0]; r[1] = (__bf16)lo[1]; r[2] = (__bf16)lo[2]; r[3] = (__bf16)lo[3];
    r[4] = (__bf16)hi[0]; r[5] = (__bf16)hi[1]; r[6] = (__bf16)hi[2]; r[7] = (__bf16)hi[3];
    return r;
}
template <int ISBF>
__device__ __forceinline__ f32x2 ld2f(const void* p, size_t elem)
{
    f32x2 r;
    if (ISBF) {
        bf16x2 v = *(const bf16x2*)((const __bf16*)p + elem);
        r[0] = (float)v[0]; r[1] = (float)v[1];
    } else {
        r = *(const f32x2*)((const float*)p + elem);
    }
    return r;
}
template <int ISBF>
__device__ __forceinline__ float ldf(const void* p, size_t elem)
{
    return ISBF ? (float)((const __bf16*)p)[elem] : ((const float*)p)[elem];
}

// ---------------------------------------------------------------------------
// Gate pre-activations G[t][n] = dot(inp[n], gate_t), fp32. (verified R3-R5)
// ---------------------------------------------------------------------------
template <int ISBF>
__device__ __forceinline__ void gate_body(
    const void* __restrict__ A,
    const void* __restrict__ g0, const void* __restrict__ g1,
    const void* __restrict__ g2, const void* __restrict__ g3,
    float* __restrict__ G, int M)
{
    int node = blockIdx.x * 4 + (threadIdx.x >> 6);
    int lane = threadIdx.x & 63;
    if (node >= M) return;
    int d = lane * 2;
    f32x2 a  = ld2f<ISBF>(A, (size_t)node * D + d);
    f32x2 v0 = ld2f<ISBF>(g0, d);
    f32x2 v1 = ld2f<ISBF>(g1, d);
    f32x2 v2 = ld2f<ISBF>(g2, d);
    f32x2 v3 = ld2f<ISBF>(g3, d);
    float s0 = a[0] * v0[0] + a[1] * v0[1];
    float s1 = a[0] * v1[0] + a[1] * v1[1];
    float s2 = a[0] * v2[0] + a[1] * v2[1];
    float s3 = a[0] * v3[0] + a[1] * v3[1];
#pragma unroll
    for (int off = 32; off > 0; off >>= 1) {
        s0 += __shfl_down(s0, off);
        s1 += __shfl_down(s1, off);
        s2 += __shfl_down(s2, off);
        s3 += __shfl_down(s3, off);
    }
    if (lane == 0) {
        G[(size_t)0 * M + node] = s0;
        G[(size_t)1 * M + node] = s1;
        G[(size_t)2 * M + node] = s2;
        G[(size_t)3 * M + node] = s3;
    }
}

__global__ __launch_bounds__(256) void gate_kernel(
    const void* __restrict__ A,
    const void* __restrict__ g0, const void* __restrict__ g1,
    const void* __restrict__ g2, const void* __restrict__ g3,
    float* __restrict__ G, int M, const int* __restrict__ flag)
{
    if (flag[0]) gate_body<1>(A, g0, g1, g2, g3, G, M);
    else         gate_body<0>(A, g0, g1, g2, g3, G, M);
}

// ---------------------------------------------------------------------------
// CSR build (verified R4/R5): histogram -> scan -> scatter
// ---------------------------------------------------------------------------
__global__ __launch_bounds__(256) void hist_kernel(
    const int* __restrict__ tgt, int* __restrict__ counts, int E)
{
    int e = blockIdx.x * 256 + threadIdx.x;
    if (e < E) atomicAdd(&counts[tgt[e]], 1);
}

__global__ __launch_bounds__(256) void scan1_kernel(
    const int* __restrict__ counts, int* __restrict__ rowptr,
    int* __restrict__ bsum, int M)
{
    __shared__ int sh[256];
    int base = blockIdx.x * 1024 + threadIdx.x * 4;
    int v[4];
#pragma unroll
    for (int k = 0; k < 4; ++k)
        v[k] = (base + k < M) ? counts[base + k] : 0;
    int tot = v[0] + v[1] + v[2] + v[3];
    sh[threadIdx.x] = tot;
    __syncthreads();
    for (int off = 1; off < 256; off <<= 1) {
        int t = (threadIdx.x >= off) ? sh[threadIdx.x - off] : 0;
        __syncthreads();
        sh[threadIdx.x] += t;
        __syncthreads();
    }
    int run = sh[threadIdx.x] - tot;
#pragma unroll
    for (int k = 0; k < 4; ++k) {
        if (base + k < M) rowptr[base + k] = run;
        run += v[k];
    }
    if (threadIdx.x == 255) bsum[blockIdx.x] = sh[255];
}

__global__ __launch_bounds__(256) void scan2_kernel(
    int* __restrict__ bsum, int* __restrict__ boff, int NB)
{
    __shared__ int sh[256];
    int base = threadIdx.x * 4;
    int v[4];
#pragma unroll
    for (int k = 0; k < 4; ++k)
        v[k] = (base + k < NB) ? bsum[base + k] : 0;
    int tot = v[0] + v[1] + v[2] + v[3];
    sh[threadIdx.x] = tot;
    __syncthreads();
    for (int off = 1; off < 256; off <<= 1) {
        int t = (threadIdx.x >= off) ? sh[threadIdx.x - off] : 0;
        __syncthreads();
        sh[threadIdx.x] += t;
        __syncthreads();
    }
    int run = sh[threadIdx.x] - tot;
#pragma unroll
    for (int k = 0; k < 4; ++k) {
        if (base + k < NB) boff[base + k] = run;
        run += v[k];
    }
}

__global__ __launch_bounds__(256) void scan3_kernel(
    int* __restrict__ rowptr, int* __restrict__ cursor,
    const int* __restrict__ boff, int M, int E)
{
    int b = blockIdx.x;
    int base = b * 1024 + threadIdx.x * 4;
    int o = boff[b];
#pragma unroll
    for (int k = 0; k < 4; ++k) {
        int i = base + k;
        if (i < M) {
            int r = rowptr[i] + o;
            rowptr[i] = r;
            cursor[i] = r;
        }
    }
    if (b == 0 && threadIdx.x == 0) rowptr[M] = E;
}

__global__ __launch_bounds__(256) void scatter_kernel(
    const int* __restrict__ deprel, const int* __restrict__ deparc,
    const int* __restrict__ src, const int* __restrict__ tgt,
    int* __restrict__ cursor, int2* __restrict__ recs, int E)
{
    int e = blockIdx.x * 256 + threadIdx.x;
    if (e >= E) return;
    int g = tgt[e];
    int pos = atomicAdd(&cursor[g], 1);
    recs[pos] = make_int2(src[e], (deprel[e] << 2) | deparc[e]);
}

// ---------------------------------------------------------------------------
// Phase A (NEW): per-target aggregation BEFORE the matmul (linearity):
//   AG[g][t*128+d] = sum_{e->g, t_e=t} gate_e * inp[s_e][d]     (bf16)
//   BA[g][d]       = sum_{e->g} gate_e * B[t_e][r_e][d]         (bf16)
// One wave per target node. inp working set = 25.6 MB -> L3-hot reads.
// All writes coalesced.
// ---------------------------------------------------------------------------
template <int ISBF>
__device__ __forceinline__ void edge_agg_body(
    const void* __restrict__ inp, const float* __restrict__ G,
    const void* __restrict__ b_in, const void* __restrict__ b_out,
    const void* __restrict__ bg_in, const void* __restrict__ bg_out,
    const int* __restrict__ rowptr, const int2* __restrict__ recs,
    __bf16* __restrict__ AG, __bf16* __restrict__ BA, int M)
{
    int g = blockIdx.x * 4 + (threadIdx.x >> 6);
    if (g >= M) return;
    int lane = threadIdx.x & 63;
    int beg = rowptr[g], end = rowptr[g + 1];
    int d = lane * 2;

    float a[4][2] = {{0.f,0.f},{0.f,0.f},{0.f,0.f},{0.f,0.f}};
    float ba0 = 0.f, ba1 = 0.f;

    for (int base = beg; base < end; base += 64) {
        int n = end - base; if (n > 64) n = 64;
        int2 rec = (lane < n) ? recs[base + lane] : make_int2(0, 0);
        int t = rec.y & 3, r = rec.y >> 2;
        float gpre = G[(size_t)t * M + rec.x];
        float bg = 0.f;
        if (t == 0)      bg = ldf<ISBF>(bg_in, r);
        else if (t == 1) bg = ldf<ISBF>(bg_out, r);
        float gate = 1.f / (1.f + __expf(-(gpre + bg)));

        for (int j = 0; j < n; ++j) {
            int sj = __shfl(rec.x, j);
            int mj = __shfl(rec.y, j);
            float gj = __shfl(gate, j);
            int tj = mj & 3, rj = mj >> 2;   // wave-uniform
            f32x2 v = ld2f<ISBF>(inp, (size_t)sj * D + d);
            if (tj == 0) {
                a[0][0] += v[0] * gj; a[0][1] += v[1] * gj;
                f32x2 bv = ld2f<ISBF>(b_in, (size_t)rj * D + d);
                ba0 += bv[0] * gj; ba1 += bv[1] * gj;
            } else if (tj == 1) {
                a[1][0] += v[0] * gj; a[1][1] += v[1] * gj;
                f32x2 bv = ld2f<ISBF>(b_out, (size_t)rj * D + d);
                ba0 += bv[0] * gj; ba1 += bv[1] * gj;
            } else if (tj == 2) {
                a[2][0] += v[0] * gj; a[2][1] += v[1] * gj;
            } else {
                a[3][0] += v[0] * gj; a[3][1] += v[1] * gj;
            }
        }
    }

    __bf16* agrow = AG + (size_t)g * (4 * D);
#pragma unroll
    for (int t = 0; t < 4; ++t) {
        bf16x2 w; w[0] = (__bf16)a[t][0]; w[1] = (__bf16)a[t][1];
        *(bf16x2*)(agrow + t * D + d) = w;
    }
    bf16x2 wb; wb[0] = (__bf16)ba0; wb[1] = (__bf16)ba1;
    *(bf16x2*)(BA + (size_t)g * D + d) = wb;
}

__global__ __launch_bounds__(256) void edge_agg_kernel(
    const void* __restrict__ inp, const float* __restrict__ G,
    const void* __restrict__ b_in, const void* __restrict__ b_out,
    const void* __restrict__ bg_in, const void* __restrict__ bg_out,
    const int* __restrict__ rowptr, const int2* __restrict__ recs,
    __bf16* __restrict__ AG, __bf16* __restrict__ BA, int M,
    const int* __restrict__ flag)
{
    if (flag[0]) edge_agg_body<1>(inp, G, b_in, b_out, bg_in, bg_out, rowptr, recs, AG, BA, M);
    else         edge_agg_body<0>(inp, G, b_in, b_out, bg_in, bg_out, rowptr, recs, AG, BA, M);
}

// ---------------------------------------------------------------------------
// Phase B (NEW): out[n][:] = AG[n][:512] @ WW[:512][:]^T + BA[n][:]
// WW[d][t*128+k] = W_t[d][k] (addressed per K-slice; not materialized).
// Block = 256 thr (4 waves), 64 nodes/block -> 1563 blocks.
// Transposed-operand MFMA (verified R5): A-op = W feature rows, B-op = nodes.
// ---------------------------------------------------------------------------
template <int ISBF>
__device__ __forceinline__ void gemm2_body(
    const __bf16* __restrict__ AG, const __bf16* __restrict__ BA,
    const void* __restrict__ W0, const void* __restrict__ W1,
    const void* __restrict__ W2, const void* __restrict__ W3,
    void* __restrict__ out, int M)
{
    const int wave = threadIdx.x >> 6;
    const int lane = threadIdx.x & 63;
    const int lrow = lane & 15;
    const int kgrp = lane >> 4;
    const int node = blockIdx.x * 64 + wave * 16 + lrow;
    int nc = (node < M) ? node : 0;   // clamped; stores guarded

    const void* Ws[4] = {W0, W1, W2, W3};

    f32x4 acc[8];
#pragma unroll
    for (int j = 0; j < 8; ++j) acc[j] = (f32x4){0.f, 0.f, 0.f, 0.f};

#pragma unroll
    for (int ks = 0; ks < 16; ++ks) {
        const int k0 = ks * 32 + kgrp * 8;      // K in [0,512)
        const int t  = k0 >> 7;
        const int kk = k0 & 127;
        bf16x8 af = *(const bf16x8*)(AG + (size_t)nc * (4 * D) + k0);
        const void* W = Ws[t];
#pragma unroll
        for (int ft = 0; ft < 8; ++ft) {
            bf16x8 wf = ld8<ISBF>(W, (size_t)(ft * 16 + lrow) * D + kk);
            acc[ft] = __builtin_amdgcn_mfma_f32_16x16x32_bf16(wf, af, acc[ft], 0, 0, 0);
        }
    }

    if (node < M) {
        // lane's 4 features per ft-tile: f0 = ft*16 + kgrp*4
#pragma unroll
        for (int ft = 0; ft < 8; ++ft) {
            int f0 = ft * 16 + kgrp * 4;
            bf16x4 bb = *(const bf16x4*)(BA + (size_t)node * D + f0);
            f32x4 v = acc[ft];
            v[0] += (float)bb[0]; v[1] += (float)bb[1];
            v[2] += (float)bb[2]; v[3] += (float)bb[3];
            if (ISBF) {
                bf16x4 w4;
                w4[0] = (__bf16)v[0]; w4[1] = (__bf16)v[1];
                w4[2] = (__bf16)v[2]; w4[3] = (__bf16)v[3];
                *(bf16x4*)((__bf16*)out + (size_t)node * D + f0) = w4;
            } else {
                *(f32x4*)((float*)out + (size_t)node * D + f0) = v;
            }
        }
    }
}

__global__ __launch_bounds__(256) void gemm2_kernel(
    const __bf16* __restrict__ AG, const __bf16* __restrict__ BA,
    const void* __restrict__ W0, const void* __restrict__ W1,
    const void* __restrict__ W2, const void* __restrict__ W3,
    void* __restrict__ out, int M, const int* __restrict__ flag)
{
    if (flag[0]) gemm2_body<1>(AG, BA, W0, W1, W2, W3, out, M);
    else         gemm2_body<0>(AG, BA, W0, W1, W2, W3, out, M);
}

__global__ void sentinel_kernel(__bf16* o, int n)
{
    int i = blockIdx.x * blockDim.x + threadIdx.x;
    if (i < n) o[i] = (__bf16)12345.0f;
}

static inline size_t align256(size_t x) { return (x + 255) & ~(size_t)255; }

extern "C" void kernel_launch(void* const* d_in, const int* in_sizes, int n_in,
                              void* d_out, int out_size, void* d_ws, size_t ws_size,
                              hipStream_t stream)
{
    const void* inp       = d_in[0];
    const int*  deprel    = (const int*)d_in[1];
    const int*  deparc    = (const int*)d_in[2];
    const int*  eidx      = (const int*)d_in[3];
    const void* V_in      = d_in[4];
    const void* b_in      = d_in[5];
    const void* V_in_g    = d_in[6];
    const void* b_in_g    = d_in[7];
    const void* V_out     = d_in[8];
    const void* b_out     = d_in[9];
    const void* V_out_g   = d_in[10];
    const void* b_out_g   = d_in[11];
    const void* W_self    = d_in[12];
    const void* W_self_g  = d_in[13];
    const void* W_norel   = d_in[14];
    const void* W_norel_g = d_in[15];

    const int M = in_sizes[0] / D;   // 100000
    const int E = in_sizes[1];       // 600000
    const int* src = eidx;
    const int* tgt = eidx + E;
    const int NB = (M + 1023) / 1024;

    size_t off = 0;
    size_t o_flag   = off; off = align256(off + sizeof(int));
    size_t o_AG     = off; off = align256(off + (size_t)M * 4 * D * sizeof(__bf16));
    size_t o_BA     = off; off = align256(off + (size_t)M * D * sizeof(__bf16));
    size_t o_G      = off; off = align256(off + (size_t)4 * M * sizeof(float));
    size_t o_counts = off; off = align256(off + (size_t)M * sizeof(int));
    size_t o_rowptr = off; off = align256(off + (size_t)(M + 1) * sizeof(int));
    size_t o_cursor = off; off = align256(off + (size_t)M * sizeof(int));
    size_t o_bsum   = off; off = align256(off + (size_t)NB * sizeof(int));
    size_t o_boff   = off; off = align256(off + (size_t)NB * sizeof(int));
    size_t o_recs   = off; off = align256(off + (size_t)E * sizeof(int2));

    if (off > ws_size) {
        sentinel_kernel<<<(out_size + 255) / 256, 256, 0, stream>>>(
            (__bf16*)d_out, out_size);
        return;
    }

    int*    flag   = (int*)((char*)d_ws + o_flag);
    __bf16* AG     = (__bf16*)((char*)d_ws + o_AG);
    __bf16* BA     = (__bf16*)((char*)d_ws + o_BA);
    float*  Gbuf   = (float*)((char*)d_ws + o_G);
    int*    counts = (int*)((char*)d_ws + o_counts);
    int*    rowptr = (int*)((char*)d_ws + o_rowptr);
    int*    cursor = (int*)((char*)d_ws + o_cursor);
    int*    bsum   = (int*)((char*)d_ws + o_bsum);
    int*    boff   = (int*)((char*)d_ws + o_boff);
    int2*   recs   = (int2*)((char*)d_ws + o_recs);

    detect_kernel<<<1, 256, 0, stream>>>((const unsigned int*)inp, flag);

    // CSR build
    hipMemsetAsync(counts, 0, (size_t)M * sizeof(int), stream);
    hist_kernel<<<(E + 255) / 256, 256, 0, stream>>>(tgt, counts, E);
    scan1_kernel<<<NB, 256, 0, stream>>>(counts, rowptr, bsum, M);
    scan2_kernel<<<1, 256, 0, stream>>>(bsum, boff, NB);
    scan3_kernel<<<NB, 256, 0, stream>>>(rowptr, cursor, boff, M, E);
    scatter_kernel<<<(E + 255) / 256, 256, 0, stream>>>(deprel, deparc, src, tgt,
                                                        cursor, recs, E);

    // gates
    gate_kernel<<<(M + 3) / 4, 256, 0, stream>>>(inp, V_in_g, V_out_g, W_self_g,
                                                 W_norel_g, Gbuf, M, flag);

    // aggregate-then-transform
    edge_agg_kernel<<<(M + 3) / 4, 256, 0, stream>>>(inp, Gbuf, b_in, b_out,
                                                     b_in_g, b_out_g,
                                                     rowptr, recs, AG, BA, M, flag);
    gemm2_kernel<<<(M + 63) / 64, 256, 0, stream>>>(AG, BA, V_in, V_out, W_self,
                                                    W_norel, d_out, M, flag);
}

// Round 7
// 368.088 us; speedup vs baseline: 1.3988x; 1.3988x over previous
//
#include <hip/hip_runtime.h>
#include <hip/hip_bf16.h>

#define D 128

typedef __bf16 bf16x8 __attribute__((ext_vector_type(8)));
typedef __bf16 bf16x4 __attribute__((ext_vector_type(4)));
typedef __bf16 bf16x2 __attribute__((ext_vector_type(2)));
typedef float  f32x4  __attribute__((ext_vector_type(4)));
typedef float  f32x2  __attribute__((ext_vector_type(2)));

// ---------------------------------------------------------------------------
// Dtype probe: 1 = bf16-packed, 0 = fp32 (R3-R6 evidence: bf16).
// ---------------------------------------------------------------------------
__global__ void detect_kernel(const unsigned int* __restrict__ w, int* flag)
{
    __shared__ int cnt[256];
    int c = 0;
#pragma unroll
    for (int i = 0; i < 4; ++i) {
        unsigned int v = w[threadIdx.x * 4 + i];
        unsigned int e = (v >> 7) & 0xFF;
        if (e >= 90 && e <= 134) ++c;
    }
    cnt[threadIdx.x] = c;
    __syncthreads();
    for (int s = 128; s > 0; s >>= 1) {
        if (threadIdx.x < s) cnt[threadIdx.x] += cnt[threadIdx.x + s];
        __syncthreads();
    }
    if (threadIdx.x == 0) flag[0] = (cnt[0] > 614) ? 1 : 0;
}

template <int ISBF>
__device__ __forceinline__ bf16x8 ld8(const void* p, size_t elem)
{
    if (ISBF) return *(const bf16x8*)((const __bf16*)p + elem);
    const f32x4* f = (const f32x4*)((const float*)p + elem);
    f32x4 lo = f[0], hi = f[1];
    bf16x8 r;
    r[0] = (__bf16)lo[0]; r[1] = (__bf16)lo[1]; r[2] = (__bf16)lo[2]; r[3] = (__bf16)lo[3];
    r[4] = (__bf16)hi[0]; r[5] = (__bf16)hi[1]; r[6] = (__bf16)hi[2]; r[7] = (__bf16)hi[3];
    return r;
}
template <int ISBF>
__device__ __forceinline__ f32x2 ld2f(const void* p, size_t elem)
{
    f32x2 r;
    if (ISBF) {
        bf16x2 v = *(const bf16x2*)((const __bf16*)p + elem);
        r[0] = (float)v[0]; r[1] = (float)v[1];
    } else {
        r = *(const f32x2*)((const float*)p + elem);
    }
    return r;
}
template <int ISBF>
__device__ __forceinline__ float ldf(const void* p, size_t elem)
{
    return ISBF ? (float)((const __bf16*)p)[elem] : ((const float*)p)[elem];
}

// ---------------------------------------------------------------------------
// Gate pre-activations G[t][n] (verified R3-R6).
// ---------------------------------------------------------------------------
template <int ISBF>
__device__ __forceinline__ void gate_body(
    const void* __restrict__ A,
    const void* __restrict__ g0, const void* __restrict__ g1,
    const void* __restrict__ g2, const void* __restrict__ g3,
    float* __restrict__ G, int M)
{
    int node = blockIdx.x * 4 + (threadIdx.x >> 6);
    int lane = threadIdx.x & 63;
    if (node >= M) return;
    int d = lane * 2;
    f32x2 a  = ld2f<ISBF>(A, (size_t)node * D + d);
    f32x2 v0 = ld2f<ISBF>(g0, d);
    f32x2 v1 = ld2f<ISBF>(g1, d);
    f32x2 v2 = ld2f<ISBF>(g2, d);
    f32x2 v3 = ld2f<ISBF>(g3, d);
    float s0 = a[0] * v0[0] + a[1] * v0[1];
    float s1 = a[0] * v1[0] + a[1] * v1[1];
    float s2 = a[0] * v2[0] + a[1] * v2[1];
    float s3 = a[0] * v3[0] + a[1] * v3[1];
#pragma unroll
    for (int off = 32; off > 0; off >>= 1) {
        s0 += __shfl_down(s0, off);
        s1 += __shfl_down(s1, off);
        s2 += __shfl_down(s2, off);
        s3 += __shfl_down(s3, off);
    }
    if (lane == 0) {
        G[(size_t)0 * M + node] = s0;
        G[(size_t)1 * M + node] = s1;
        G[(size_t)2 * M + node] = s2;
        G[(size_t)3 * M + node] = s3;
    }
}

__global__ __launch_bounds__(256) void gate_kernel(
    const void* __restrict__ A,
    const void* __restrict__ g0, const void* __restrict__ g1,
    const void* __restrict__ g2, const void* __restrict__ g3,
    float* __restrict__ G, int M, const int* __restrict__ flag)
{
    if (flag[0]) gate_body<1>(A, g0, g1, g2, g3, G, M);
    else         gate_body<0>(A, g0, g1, g2, g3, G, M);
}

// ---------------------------------------------------------------------------
// CSR build (verified R4-R6)
// ---------------------------------------------------------------------------
__global__ __launch_bounds__(256) void hist_kernel(
    const int* __restrict__ tgt, int* __restrict__ counts, int E)
{
    int e = blockIdx.x * 256 + threadIdx.x;
    if (e < E) atomicAdd(&counts[tgt[e]], 1);
}

__global__ __launch_bounds__(256) void scan1_kernel(
    const int* __restrict__ counts, int* __restrict__ rowptr,
    int* __restrict__ bsum, int M)
{
    __shared__ int sh[256];
    int base = blockIdx.x * 1024 + threadIdx.x * 4;
    int v[4];
#pragma unroll
    for (int k = 0; k < 4; ++k)
        v[k] = (base + k < M) ? counts[base + k] : 0;
    int tot = v[0] + v[1] + v[2] + v[3];
    sh[threadIdx.x] = tot;
    __syncthreads();
    for (int off = 1; off < 256; off <<= 1) {
        int t = (threadIdx.x >= off) ? sh[threadIdx.x - off] : 0;
        __syncthreads();
        sh[threadIdx.x] += t;
        __syncthreads();
    }
    int run = sh[threadIdx.x] - tot;
#pragma unroll
    for (int k = 0; k < 4; ++k) {
        if (base + k < M) rowptr[base + k] = run;
        run += v[k];
    }
    if (threadIdx.x == 255) bsum[blockIdx.x] = sh[255];
}

__global__ __launch_bounds__(256) void scan2_kernel(
    int* __restrict__ bsum, int* __restrict__ boff, int NB)
{
    __shared__ int sh[256];
    int base = threadIdx.x * 4;
    int v[4];
#pragma unroll
    for (int k = 0; k < 4; ++k)
        v[k] = (base + k < NB) ? bsum[base + k] : 0;
    int tot = v[0] + v[1] + v[2] + v[3];
    sh[threadIdx.x] = tot;
    __syncthreads();
    for (int off = 1; off < 256; off <<= 1) {
        int t = (threadIdx.x >= off) ? sh[threadIdx.x - off] : 0;
        __syncthreads();
        sh[threadIdx.x] += t;
        __syncthreads();
    }
    int run = sh[threadIdx.x] - tot;
#pragma unroll
    for (int k = 0; k < 4; ++k) {
        if (base + k < NB) boff[base + k] = run;
        run += v[k];
    }
}

__global__ __launch_bounds__(256) void scan3_kernel(
    int* __restrict__ rowptr, int* __restrict__ cursor,
    const int* __restrict__ boff, int M, int E)
{
    int b = blockIdx.x;
    int base = b * 1024 + threadIdx.x * 4;
    int o = boff[b];
#pragma unroll
    for (int k = 0; k < 4; ++k) {
        int i = base + k;
        if (i < M) {
            int r = rowptr[i] + o;
            rowptr[i] = r;
            cursor[i] = r;
        }
    }
    if (b == 0 && threadIdx.x == 0) rowptr[M] = E;
}

__global__ __launch_bounds__(256) void scatter_kernel(
    const int* __restrict__ deprel, const int* __restrict__ deparc,
    const int* __restrict__ src, const int* __restrict__ tgt,
    int* __restrict__ cursor, int2* __restrict__ recs, int E)
{
    int e = blockIdx.x * 256 + threadIdx.x;
    if (e >= E) return;
    int g = tgt[e];
    int pos = atomicAdd(&cursor[g], 1);
    recs[pos] = make_int2(src[e], (deprel[e] << 2) | deparc[e]);
}

// ---------------------------------------------------------------------------
// Phase A: per-target aggregation. One wave per node; 4 edges in parallel
// (16 lanes per edge, 8 dims/lane) -> 4 loads in flight per wave.
// ---------------------------------------------------------------------------
template <int ISBF>
__device__ __forceinline__ void edge_agg_body(
    const void* __restrict__ inp, const float* __restrict__ G,
    const void* __restrict__ b_in, const void* __restrict__ b_out,
    const void* __restrict__ bg_in, const void* __restrict__ bg_out,
    const int* __restrict__ rowptr, const int2* __restrict__ recs,
    __bf16* __restrict__ AG, __bf16* __restrict__ BA, int M)
{
    int g = blockIdx.x * 4 + (threadIdx.x >> 6);
    if (g >= M) return;
    int lane = threadIdx.x & 63;
    int g4 = lane >> 4;          // edge-slot within a 4-edge step
    int lane16 = lane & 15;      // dim group: dims lane16*8 .. +8
    int beg = rowptr[g], end = rowptr[g + 1];
    int dd = lane16 * 8;

    float a[4][8];
#pragma unroll
    for (int t = 0; t < 4; ++t)
#pragma unroll
        for (int k = 0; k < 8; ++k) a[t][k] = 0.f;
    float ba[8];
#pragma unroll
    for (int k = 0; k < 8; ++k) ba[k] = 0.f;

    for (int base = beg; base < end; base += 64) {
        int n = end - base; if (n > 64) n = 64;
        int2 rec = (lane < n) ? recs[base + lane] : make_int2(0, 0);
        int t = rec.y & 3, r = rec.y >> 2;
        float gpre = G[(size_t)t * M + rec.x];
        float bg = 0.f;
        if (t == 0)      bg = ldf<ISBF>(bg_in, r);
        else if (t == 1) bg = ldf<ISBF>(bg_out, r);
        float gate = 1.f / (1.f + __expf(-(gpre + bg)));

        int nj4 = (n + 3) >> 2;
        for (int jj = 0; jj < nj4; ++jj) {
            int el = jj * 4 + g4;            // this group's edge index
            int sj = __shfl(rec.x, el);
            int mj = __shfl(rec.y, el);
            float gj = __shfl(gate, el);
            if (el < n) {
                int tj = mj & 3, rj = mj >> 2;   // group-uniform
                bf16x8 v = ld8<ISBF>(inp, (size_t)sj * D + dd);
                float vf[8];
#pragma unroll
                for (int k = 0; k < 8; ++k) vf[k] = (float)v[k];
                if (tj == 0) {
                    bf16x8 bv = ld8<ISBF>(b_in, (size_t)rj * D + dd);
#pragma unroll
                    for (int k = 0; k < 8; ++k) {
                        a[0][k] += vf[k] * gj;
                        ba[k] += (float)bv[k] * gj;
                    }
                } else if (tj == 1) {
                    bf16x8 bv = ld8<ISBF>(b_out, (size_t)rj * D + dd);
#pragma unroll
                    for (int k = 0; k < 8; ++k) {
                        a[1][k] += vf[k] * gj;
                        ba[k] += (float)bv[k] * gj;
                    }
                } else if (tj == 2) {
#pragma unroll
                    for (int k = 0; k < 8; ++k) a[2][k] += vf[k] * gj;
                } else {
#pragma unroll
                    for (int k = 0; k < 8; ++k) a[3][k] += vf[k] * gj;
                }
            }
        }
    }

    // combine the 4 edge-groups (lanes l, l^16, l^32, l^48 hold same dims)
#pragma unroll
    for (int t = 0; t < 4; ++t)
#pragma unroll
        for (int k = 0; k < 8; ++k) {
            a[t][k] += __shfl_xor(a[t][k], 16);
            a[t][k] += __shfl_xor(a[t][k], 32);
        }
#pragma unroll
    for (int k = 0; k < 8; ++k) {
        ba[k] += __shfl_xor(ba[k], 16);
        ba[k] += __shfl_xor(ba[k], 32);
    }

    // group g4 writes type t = g4 (all lanes hold full sums post-reduction)
    __bf16* agrow = AG + (size_t)g * (4 * D);
    bf16x8 w;
    if (g4 == 0) {
#pragma unroll
        for (int k = 0; k < 8; ++k) w[k] = (__bf16)a[0][k];
        *(bf16x8*)(agrow + 0 * D + dd) = w;
        bf16x8 wb;
#pragma unroll
        for (int k = 0; k < 8; ++k) wb[k] = (__bf16)ba[k];
        *(bf16x8*)(BA + (size_t)g * D + dd) = wb;
    } else if (g4 == 1) {
#pragma unroll
        for (int k = 0; k < 8; ++k) w[k] = (__bf16)a[1][k];
        *(bf16x8*)(agrow + 1 * D + dd) = w;
    } else if (g4 == 2) {
#pragma unroll
        for (int k = 0; k < 8; ++k) w[k] = (__bf16)a[2][k];
        *(bf16x8*)(agrow + 2 * D + dd) = w;
    } else {
#pragma unroll
        for (int k = 0; k < 8; ++k) w[k] = (__bf16)a[3][k];
        *(bf16x8*)(agrow + 3 * D + dd) = w;
    }
}

__global__ __launch_bounds__(256) void edge_agg_kernel(
    const void* __restrict__ inp, const float* __restrict__ G,
    const void* __restrict__ b_in, const void* __restrict__ b_out,
    const void* __restrict__ bg_in, const void* __restrict__ bg_out,
    const int* __restrict__ rowptr, const int2* __restrict__ recs,
    __bf16* __restrict__ AG, __bf16* __restrict__ BA, int M,
    const int* __restrict__ flag)
{
    if (flag[0]) edge_agg_body<1>(inp, G, b_in, b_out, bg_in, bg_out, rowptr, recs, AG, BA, M);
    else         edge_agg_body<0>(inp, G, b_in, b_out, bg_in, bg_out, rowptr, recs, AG, BA, M);
}

// ---------------------------------------------------------------------------
// Phase B: out = AG[M,512] @ WW^T + BA, W staged in LDS (XOR-swizzled).
// Block = 256 thr / 128 nodes. Loop t: stage W_t (32KB) -> LDS, each wave
// does 2 node-tiles x 8 f-tiles, wf from ds_read_b128 (shared by 2 tiles).
// ---------------------------------------------------------------------------
template <int ISBF>
__device__ __forceinline__ void gemm2_body(
    const __bf16* __restrict__ AG, const __bf16* __restrict__ BA,
    const void* __restrict__ W0, const void* __restrict__ W1,
    const void* __restrict__ W2, const void* __restrict__ W3,
    void* __restrict__ out, int M)
{
    __shared__ __bf16 Wsh[128 * 128];   // 32 KB, row f: 16 slots of 16B, swizzled

    const int wave = threadIdx.x >> 6;
    const int lane = threadIdx.x & 63;
    const int lrow = lane & 15;
    const int kgrp = lane >> 4;
    const int m_base = blockIdx.x * 128 + wave * 32;

    int n0 = m_base + lrow;      if (n0 >= M) n0 = 0;   // clamped; stores guarded
    int n1 = m_base + 16 + lrow; if (n1 >= M) n1 = 0;

    const void* Ws[4] = {W0, W1, W2, W3};

    f32x4 acc[2][8];
#pragma unroll
    for (int i = 0; i < 2; ++i)
#pragma unroll
        for (int j = 0; j < 8; ++j)
            acc[i][j] = (f32x4){0.f, 0.f, 0.f, 0.f};

    for (int t = 0; t < 4; ++t) {
        // stage W_t: 2048 16B-slots; thread tid handles slots tid, tid+256, ...
        const void* W = Ws[t];
#pragma unroll
        for (int i = 0; i < 8; ++i) {
            int slot = threadIdx.x + 256 * i;
            int f = slot >> 4;
            int s = slot & 15;
            int sp = s ^ (f & 7);
            bf16x8 v = ld8<ISBF>(W, (size_t)f * D + s * 8);
            *(bf16x8*)(Wsh + f * 128 + sp * 8) = v;
        }
        __syncthreads();

#pragma unroll
        for (int ks = 0; ks < 4; ++ks) {
            const int k0 = ks * 32 + kgrp * 8;                 // k within t
            bf16x8 af0 = *(const bf16x8*)(AG + (size_t)n0 * (4 * D) + t * D + k0);
            bf16x8 af1 = *(const bf16x8*)(AG + (size_t)n1 * (4 * D) + t * D + k0);
            const int slot = 4 * ks + kgrp;                    // 16B slot index
#pragma unroll
            for (int ft = 0; ft < 8; ++ft) {
                int f = ft * 16 + lrow;
                int sp = slot ^ (f & 7);
                bf16x8 wf = *(const bf16x8*)(Wsh + f * 128 + sp * 8);
                acc[0][ft] = __builtin_amdgcn_mfma_f32_16x16x32_bf16(wf, af0, acc[0][ft], 0, 0, 0);
                acc[1][ft] = __builtin_amdgcn_mfma_f32_16x16x32_bf16(wf, af1, acc[1][ft], 0, 0, 0);
            }
        }
        __syncthreads();
    }

    // epilogue (layout verified R5/R6): node = col, features = kgrp*4+reg +ft*16
#pragma unroll
    for (int nt = 0; nt < 2; ++nt) {
        int node = m_base + nt * 16 + lrow;
        if (node < M) {
#pragma unroll
            for (int ft = 0; ft < 8; ++ft) {
                int f0 = ft * 16 + kgrp * 4;
                bf16x4 bb = *(const bf16x4*)(BA + (size_t)node * D + f0);
                f32x4 v = acc[nt][ft];
                v[0] += (float)bb[0]; v[1] += (float)bb[1];
                v[2] += (float)bb[2]; v[3] += (float)bb[3];
                if (ISBF) {
                    bf16x4 w4;
                    w4[0] = (__bf16)v[0]; w4[1] = (__bf16)v[1];
                    w4[2] = (__bf16)v[2]; w4[3] = (__bf16)v[3];
                    *(bf16x4*)((__bf16*)out + (size_t)node * D + f0) = w4;
                } else {
                    *(f32x4*)((float*)out + (size_t)node * D + f0) = v;
                }
            }
        }
    }
}

__global__ __launch_bounds__(256) void gemm2_kernel(
    const __bf16* __restrict__ AG, const __bf16* __restrict__ BA,
    const void* __restrict__ W0, const void* __restrict__ W1,
    const void* __restrict__ W2, const void* __restrict__ W3,
    void* __restrict__ out, int M, const int* __restrict__ flag)
{
    if (flag[0]) gemm2_body<1>(AG, BA, W0, W1, W2, W3, out, M);
    else         gemm2_body<0>(AG, BA, W0, W1, W2, W3, out, M);
}

__global__ void sentinel_kernel(__bf16* o, int n)
{
    int i = blockIdx.x * blockDim.x + threadIdx.x;
    if (i < n) o[i] = (__bf16)12345.0f;
}

static inline size_t align256(size_t x) { return (x + 255) & ~(size_t)255; }

extern "C" void kernel_launch(void* const* d_in, const int* in_sizes, int n_in,
                              void* d_out, int out_size, void* d_ws, size_t ws_size,
                              hipStream_t stream)
{
    const void* inp       = d_in[0];
    const int*  deprel    = (const int*)d_in[1];
    const int*  deparc    = (const int*)d_in[2];
    const int*  eidx      = (const int*)d_in[3];
    const void* V_in      = d_in[4];
    const void* b_in      = d_in[5];
    const void* V_in_g    = d_in[6];
    const void* b_in_g    = d_in[7];
    const void* V_out     = d_in[8];
    const void* b_out     = d_in[9];
    const void* V_out_g   = d_in[10];
    const void* b_out_g   = d_in[11];
    const void* W_self    = d_in[12];
    const void* W_self_g  = d_in[13];
    const void* W_norel   = d_in[14];
    const void* W_norel_g = d_in[15];

    const int M = in_sizes[0] / D;   // 100000
    const int E = in_sizes[1];       // 600000
    const int* src = eidx;
    const int* tgt = eidx + E;
    const int NB = (M + 1023) / 1024;

    size_t off = 0;
    size_t o_flag   = off; off = align256(off + sizeof(int));
    size_t o_AG     = off; off = align256(off + (size_t)M * 4 * D * sizeof(__bf16));
    size_t o_BA     = off; off = align256(off + (size_t)M * D * sizeof(__bf16));
    size_t o_G      = off; off = align256(off + (size_t)4 * M * sizeof(float));
    size_t o_counts = off; off = align256(off + (size_t)M * sizeof(int));
    size_t o_rowptr = off; off = align256(off + (size_t)(M + 1) * sizeof(int));
    size_t o_cursor = off; off = align256(off + (size_t)M * sizeof(int));
    size_t o_bsum   = off; off = align256(off + (size_t)NB * sizeof(int));
    size_t o_boff   = off; off = align256(off + (size_t)NB * sizeof(int));
    size_t o_recs   = off; off = align256(off + (size_t)E * sizeof(int2));

    if (off > ws_size) {
        sentinel_kernel<<<(out_size + 255) / 256, 256, 0, stream>>>(
            (__bf16*)d_out, out_size);
        return;
    }

    int*    flag   = (int*)((char*)d_ws + o_flag);
    __bf16* AG     = (__bf16*)((char*)d_ws + o_AG);
    __bf16* BA     = (__bf16*)((char*)d_ws + o_BA);
    float*  Gbuf   = (float*)((char*)d_ws + o_G);
    int*    counts = (int*)((char*)d_ws + o_counts);
    int*    rowptr = (int*)((char*)d_ws + o_rowptr);
    int*    cursor = (int*)((char*)d_ws + o_cursor);
    int*    bsum   = (int*)((char*)d_ws + o_bsum);
    int*    boff   = (int*)((char*)d_ws + o_boff);
    int2*   recs   = (int2*)((char*)d_ws + o_recs);

    detect_kernel<<<1, 256, 0, stream>>>((const unsigned int*)inp, flag);

    // CSR build
    hipMemsetAsync(counts, 0, (size_t)M * sizeof(int), stream);
    hist_kernel<<<(E + 255) / 256, 256, 0, stream>>>(tgt, counts, E);
    scan1_kernel<<<NB, 256, 0, stream>>>(counts, rowptr, bsum, M);
    scan2_kernel<<<1, 256, 0, stream>>>(bsum, boff, NB);
    scan3_kernel<<<NB, 256, 0, stream>>>(rowptr, cursor, boff, M, E);
    scatter_kernel<<<(E + 255) / 256, 256, 0, stream>>>(deprel, deparc, src, tgt,
                                                        cursor, recs, E);

    // gates
    gate_kernel<<<(M + 3) / 4, 256, 0, stream>>>(inp, V_in_g, V_out_g, W_self_g,
                                                 W_norel_g, Gbuf, M, flag);

    // aggregate-then-transform
    edge_agg_kernel<<<(M + 3) / 4, 256, 0, stream>>>(inp, Gbuf, b_in, b_out,
                                                     b_in_g, b_out_g,
                                                     rowptr, recs, AG, BA, M, flag);
    gemm2_kernel<<<(M + 127) / 128, 256, 0, stream>>>(AG, BA, V_in, V_out, W_self,
                                                      W_norel, d_out, M, flag);
}